// Round 1
// baseline (595.510 us; speedup 1.0000x reference)
//
#include <hip/hip_runtime.h>
#include <hip/hip_bf16.h>

// ---- problem constants (from setup_inputs) ----
#define B_   2
#define T_   4160
#define D_   1024
#define H_   16
#define KVH_ 4
#define HD_  64
#define UPD  2048          // update_start
#define NU   2112          // n_update = T - UPD
#define MQ   (B_*NU)       // 4224 rows of updated tokens
#define MT   (B_*T_)       // 8320 rows total

typedef unsigned short u16;
typedef __attribute__((ext_vector_type(8))) short bf16x8;
typedef __attribute__((ext_vector_type(4))) float f32x4;
typedef __attribute__((ext_vector_type(4))) unsigned short u16x4;

__device__ __forceinline__ float bf2f(u16 u){ return __uint_as_float(((unsigned)u)<<16); }
__device__ __forceinline__ u16 f2bf(float f){
  unsigned u = __float_as_uint(f);
  u += 0x7FFF + ((u>>16)&1);           // RNE
  return (u16)(u>>16);
}

// async global->LDS, 16B per lane; lds dst must be wave-uniform base (+lane*16 by HW)
__device__ __forceinline__ void gll16(const void* g, void* l){
  __builtin_amdgcn_global_load_lds((const __attribute__((address_space(1))) char*)g,
                                   (__attribute__((address_space(3))) char*)l, 16, 0, 0);
}

// ---------------- elementwise: f32 -> bf16 cast ----------------
__global__ void cast_bf16(const float* __restrict__ in, u16* __restrict__ o, int n){
  int i = blockIdx.x*blockDim.x + threadIdx.x;
  if (i*4 < n){
    float4 v = ((const float4*)in)[i];
    u16x4 u; u.x=f2bf(v.x); u.y=f2bf(v.y); u.z=f2bf(v.z); u.w=f2bf(v.w);
    ((u16x4*)o)[i] = u;
  }
}

// ---------------- RMSNorm (one 256-thread block per row of 1024) ----------------
// withcopy: also copy raw fp32 rows with (row % T_) < UPD into copy_out (prefix passthrough)
__global__ void rmsnorm_kernel(const float* __restrict__ in, u16* __restrict__ obf,
                               float* __restrict__ copy_out, int withcopy){
  int row = blockIdx.x;
  int t = threadIdx.x;
  const float* xr = in + (size_t)row*D_;
  float4 v = ((const float4*)xr)[t];
  float ss = v.x*v.x + v.y*v.y + v.z*v.z + v.w*v.w;
  #pragma unroll
  for (int o=32;o;o>>=1) ss += __shfl_xor(ss, o);
  __shared__ float red[4];
  if ((t&63)==0) red[t>>6] = ss;
  __syncthreads();
  float tot = red[0]+red[1]+red[2]+red[3];
  float sc = rsqrtf(tot*(1.0f/D_) + 1e-6f);
  u16x4 o4; o4.x=f2bf(v.x*sc); o4.y=f2bf(v.y*sc); o4.z=f2bf(v.z*sc); o4.w=f2bf(v.w*sc);
  ((u16x4*)(obf + (size_t)row*D_))[t] = o4;
  if (withcopy && (row % T_) < UPD)
    ((float4*)(copy_out + (size_t)row*D_))[t] = v;
}

// ---------------- L2-normalize contiguous 64-element vectors ----------------
__global__ void l2norm_kernel(u16* __restrict__ buf, int nvec){
  int vid = blockIdx.x*4 + (threadIdx.x>>6);
  int ln = threadIdx.x & 63;
  if (vid >= nvec) return;
  u16* p = buf + (size_t)vid*64 + ln;
  float x = bf2f(*p);
  float ss = x*x;
  #pragma unroll
  for (int o=32;o;o>>=1) ss += __shfl_xor(ss, o);
  float n = sqrtf(ss);
  n = (n < 1e-12f) ? 1e-12f : n;
  *p = f2bf(x / n);
}

// ---------------- bf16 GEMM: C[M,N] = A[M,K] * B[N,K]^T ----------------
// 128x128 tile, BK=32, 4 waves (2x2), 16x16x32 MFMA, global_load_lds staging,
// 2-phase prefetch (stage next while computing current).
// EPI: 0=store bf16   1=softcap-tanh + x residual -> fp32 x_new
//      2=relu^2 -> bf16   3=x_new residual -> fp32 out (row-remapped)
// AMAP: 0 identity; 1: A row r -> (r/NU)*T_ + UPD + r%NU  (x_upd slice of x_norm)
template<int EPI, int AMAP>
__global__ __launch_bounds__(256) void gemm_bt(
    const u16* __restrict__ A, const u16* __restrict__ Bw, void* __restrict__ C,
    const float* __restrict__ aux, int M, int N, int K)
{
  __shared__ alignas(16) u16 sA[2][4096];   // [128][32]
  __shared__ alignas(16) u16 sB[2][4096];
  int m0 = blockIdx.y*128, n0 = blockIdx.x*128;
  int tid = threadIdx.x;
  int wv = tid>>6, ln = tid&63;
  int wr = wv>>1, wc = wv&1;
  int lr = ln&15, lg = ln>>4;

  auto stage = [&](int bu, int kt){
    #pragma unroll
    for (int c=0;c<2;c++){
      int ci = c*256 + tid;
      int row = ci>>2, colb = (ci&3)*16;
      int arow = m0 + row;
      if (AMAP==1) arow = (arow/NU)*T_ + UPD + (arow%NU);
      const u16* src = A + (size_t)arow*K + kt*32 + (colb>>1);
      gll16(src, (char*)sA[bu] + (c*256 + wv*64)*16);
    }
    #pragma unroll
    for (int c=0;c<2;c++){
      int ci = c*256 + tid;
      int row = ci>>2, colb = (ci&3)*16;
      const u16* src = Bw + (size_t)(n0+row)*K + kt*32 + (colb>>1);
      gll16(src, (char*)sB[bu] + (c*256 + wv*64)*16);
    }
  };

  f32x4 acc[4][4] = {};
  int nk = K>>5;
  stage(0,0);
  __syncthreads();
  for (int kt=0; kt<nk; ++kt){
    int bu = kt&1;
    if (kt+1<nk) stage(bu^1, kt+1);
    bf16x8 af[4], bfr[4];
    #pragma unroll
    for (int i=0;i<4;i++){
      af[i]  = *(const bf16x8*)&sA[bu][(wr*64 + i*16 + lr)*32 + lg*8];
      bfr[i] = *(const bf16x8*)&sB[bu][(wc*64 + i*16 + lr)*32 + lg*8];
    }
    #pragma unroll
    for (int i=0;i<4;i++)
      #pragma unroll
      for (int j=0;j<4;j++)
        acc[i][j] = __builtin_amdgcn_mfma_f32_16x16x32_bf16(af[i], bfr[j], acc[i][j], 0,0,0);
    __syncthreads();
  }
  #pragma unroll
  for (int i=0;i<4;i++)
    #pragma unroll
    for (int j=0;j<4;j++)
      #pragma unroll
      for (int r=0;r<4;r++){
        int grow = m0 + wr*64 + i*16 + lg*4 + r;
        int gcol = n0 + wc*64 + j*16 + lr;
        float cv = acc[i][j][r];
        if (EPI==0){
          ((u16*)C)[(size_t)grow*N + gcol] = f2bf(cv);
        } else if (EPI==1){
          int b = grow/NU, t = grow - b*NU;
          float e = __expf(cv*(2.0f/15.0f));
          float val = 15.f*(e-1.f)/(e+1.f) + aux[((size_t)(b*T_ + UPD + t))*D_ + gcol];
          ((float*)C)[(size_t)grow*N + gcol] = val;
        } else if (EPI==2){
          float rr = cv>0.f ? cv : 0.f;
          ((u16*)C)[(size_t)grow*N + gcol] = f2bf(rr*rr);
        } else {
          int b = grow/NU, t = grow - b*NU;
          float val = aux[(size_t)grow*N + gcol] + cv;
          ((float*)C)[((size_t)(b*T_ + UPD + t))*D_ + gcol] = val;
        }
      }
}

// ---------------- attention ----------------
// grid (qt=33, h=16, b=2), 256 thr = 4 waves, each wave owns 16 q-rows.
// Scores s = q.k in [-1,1] (L2-normed) -> exp(s/8) needs NO max subtraction:
// accumulate num += P@V, den += P@1 linearly; divide at the end.
// K staged via global_load_lds with XOR swizzle (pre-swizzled global source);
// V staged transposed ([64 d][64 k]) via column gathers + swizzled b128 writes.
__global__ __launch_bounds__(256) void attn_kernel(
    const u16* __restrict__ qb, const u16* __restrict__ kb,
    const u16* __restrict__ vb, u16* __restrict__ ab)
{
  __shared__ alignas(16) u16 sK[64*64];     // [64 k][64 d], swizzled
  __shared__ alignas(16) u16 sVt[64*64];    // [64 d][64 k], swizzled
  __shared__ alignas(16) u16 sP[4][16*64];  // per-wave P tile
  int qt = blockIdx.x, h = blockIdx.y, b = blockIdx.z;
  int tid = threadIdx.x, wv = tid>>6, ln = tid&63;
  int lr = ln&15, lg = ln>>4;
  int kh = h>>2;
  int qbg = UPD + qt*64;

  bf16x8 qf[2];
  {
    const u16* qp = qb + (size_t)(b*NU + qt*64 + wv*16 + lr)*D_ + h*HD_;
    qf[0] = *(const bf16x8*)(qp + lg*8);
    qf[1] = *(const bf16x8*)(qp + 32 + lg*8);
  }
  bf16x8 ones;
  #pragma unroll
  for (int i=0;i<8;i++) ones[i] = (short)0x3F80;

  f32x4 accO[4] = {};
  f32x4 accD = {};

  int nkt = qt + 33;                      // keys 0 .. qbg+63 in tiles of 64
  for (int kt=0; kt<nkt; ++kt){
    __syncthreads();                      // prev iter's reads done before overwrite
    // --- stage K tile [64][64] (8KB), two 16B chunks/thread, swizzled source ---
    #pragma unroll
    for (int cc=0; cc<2; ++cc){
      int ci = cc*256 + tid;
      int row = ci>>3, slotb = (ci&7)*16;
      int scolb = slotb ^ ((row&7)<<4);
      const u16* src = kb + (size_t)(b*T_ + kt*64 + row)*256 + kh*HD_ + (scolb>>1);
      gll16(src, (char*)sK + (cc*256 + wv*64)*16);
    }
    // --- stage V transposed: thread owns column c=tid>>2, k-range (tid&3)*16..+15 ---
    {
      int c = tid>>2, r0 = (tid&3)*16;
      #pragma unroll
      for (int half=0; half<2; ++half){
        int k0 = r0 + half*8;
        bf16x8 pk;
        #pragma unroll
        for (int j=0;j<8;j++)
          pk[j] = (short)vb[(size_t)(b*T_ + kt*64 + k0 + j)*256 + kh*HD_ + c];
        *(bf16x8*)((char*)sVt + c*128 + ((k0*2) ^ ((c&7)<<4))) = pk;
      }
    }
    __syncthreads();

    // --- S = Q K^T (4 k-subtiles of 16) ---
    f32x4 s[4] = {};
    #pragma unroll
    for (int kt2=0; kt2<4; ++kt2){
      int row = kt2*16 + lr;
      int sw = (row&7)<<4;
      bf16x8 k0 = *(const bf16x8*)((const char*)sK + row*128 + ((lg*16) ^ sw));
      bf16x8 k1 = *(const bf16x8*)((const char*)sK + row*128 + ((64 + lg*16) ^ sw));
      s[kt2] = __builtin_amdgcn_mfma_f32_16x16x32_bf16(qf[0], k0, s[kt2], 0,0,0);
      s[kt2] = __builtin_amdgcn_mfma_f32_16x16x32_bf16(qf[1], k1, s[kt2], 0,0,0);
    }
    // --- mask + exp -> P (bf16, via per-wave LDS; same-wave so no barrier) ---
    int ktb = kt*64;
    #pragma unroll
    for (int kt2=0; kt2<4; ++kt2)
      #pragma unroll
      for (int r=0;r<4;r++){
        int kpos = ktb + kt2*16 + lr;
        int qpos = qbg + wv*16 + lg*4 + r;
        float p = (kpos <= qpos) ? __expf(s[kt2][r]*0.125f) : 0.0f;
        sP[wv][(lg*4+r)*64 + kt2*16 + lr] = f2bf(p);
      }
    bf16x8 pf0 = *(const bf16x8*)&sP[wv][lr*64 + lg*8];
    bf16x8 pf1 = *(const bf16x8*)&sP[wv][lr*64 + 32 + lg*8];
    // --- O += P V, den += P 1 ---
    #pragma unroll
    for (int dt=0; dt<4; ++dt){
      int d = dt*16 + lr;
      int sw = (d&7)<<4;
      bf16x8 v0 = *(const bf16x8*)((const char*)sVt + d*128 + ((lg*16) ^ sw));
      bf16x8 v1 = *(const bf16x8*)((const char*)sVt + d*128 + ((64 + lg*16) ^ sw));
      accO[dt] = __builtin_amdgcn_mfma_f32_16x16x32_bf16(pf0, v0, accO[dt], 0,0,0);
      accO[dt] = __builtin_amdgcn_mfma_f32_16x16x32_bf16(pf1, v1, accO[dt], 0,0,0);
    }
    accD = __builtin_amdgcn_mfma_f32_16x16x32_bf16(pf0, ones, accD, 0,0,0);
    accD = __builtin_amdgcn_mfma_f32_16x16x32_bf16(pf1, ones, accD, 0,0,0);
  }
  #pragma unroll
  for (int dt=0; dt<4; ++dt)
    #pragma unroll
    for (int r=0;r<4;r++){
      float val = accO[dt][r] / accD[r];
      size_t row = (size_t)(b*NU + qt*64 + wv*16 + lg*4 + r);
      ab[row*D_ + h*HD_ + dt*16 + lr] = f2bf(val);
    }
}

// ---------------- launch ----------------
extern "C" void kernel_launch(void* const* d_in, const int* in_sizes, int n_in,
                              void* d_out, int out_size, void* d_ws, size_t ws_size,
                              hipStream_t stream)
{
  const float* x     = (const float*)d_in[0];
  const float* Wq    = (const float*)d_in[1];
  const float* Wk    = (const float*)d_in[2];
  const float* Wv    = (const float*)d_in[3];
  const float* Wo    = (const float*)d_in[4];
  const float* Wfc   = (const float*)d_in[5];
  const float* Wproj = (const float*)d_in[6];
  float* out = (float*)d_out;

  char* ws = (char*)d_ws;
  size_t off = 0;
  auto alloc = [&](size_t bytes)->char*{ char* p = ws + off; off += (bytes + 255) & ~(size_t)255; return p; };
  u16* wqb  = (u16*)alloc((size_t)D_*D_*2);
  u16* wkb  = (u16*)alloc((size_t)256*D_*2);
  u16* wvb  = (u16*)alloc((size_t)256*D_*2);
  u16* wob  = (u16*)alloc((size_t)D_*D_*2);
  u16* wfcb = (u16*)alloc((size_t)4096*D_*2);
  u16* wpb  = (u16*)alloc((size_t)D_*4096*2);
  u16* xn   = (u16*)alloc((size_t)MT*D_*2);
  u16* qB   = (u16*)alloc((size_t)MQ*D_*2);
  u16* kB   = (u16*)alloc((size_t)MT*256*2);
  u16* vB   = (u16*)alloc((size_t)MT*256*2);
  u16* aB   = (u16*)alloc((size_t)MQ*D_*2);
  float* xnew = (float*)alloc((size_t)MQ*D_*4);
  u16* xn2  = (u16*)alloc((size_t)MQ*D_*2);
  u16* hB   = (u16*)alloc((size_t)MQ*4096*2);
  (void)ws_size; (void)in_sizes; (void)n_in; (void)out_size;

  // weights -> bf16
  cast_bf16<<<1024, 256, 0, stream>>>(Wq, wqb, D_*D_);
  cast_bf16<<<256,  256, 0, stream>>>(Wk, wkb, 256*D_);
  cast_bf16<<<256,  256, 0, stream>>>(Wv, wvb, 256*D_);
  cast_bf16<<<1024, 256, 0, stream>>>(Wo, wob, D_*D_);
  cast_bf16<<<4096, 256, 0, stream>>>(Wfc, wfcb, 4096*D_);
  cast_bf16<<<4096, 256, 0, stream>>>(Wproj, wpb, D_*4096);

  // x_norm (bf16) + passthrough copy of prefix rows to out
  rmsnorm_kernel<<<MT, 256, 0, stream>>>(x, xn, out, 1);

  // projections
  gemm_bt<0,1><<<dim3(8,33),  256, 0, stream>>>(xn, wqb, qB, nullptr, MQ, D_,  D_);
  gemm_bt<0,0><<<dim3(2,65),  256, 0, stream>>>(xn, wkb, kB, nullptr, MT, 256, D_);
  gemm_bt<0,0><<<dim3(2,65),  256, 0, stream>>>(xn, wvb, vB, nullptr, MT, 256, D_);

  // L2 normalize q (per head-vector of 64) and k
  l2norm_kernel<<<(MQ*H_)/4, 256, 0, stream>>>(qB, MQ*H_);
  l2norm_kernel<<<(MT*KVH_)/4, 256, 0, stream>>>(kB, MT*KVH_);

  // attention
  attn_kernel<<<dim3(33,16,2), 256, 0, stream>>>(qB, kB, vB, aB);

  // out-proj + softcap + residual -> x_new (fp32)
  gemm_bt<1,0><<<dim3(8,33),  256, 0, stream>>>(aB, wob, xnew, x, MQ, D_, D_);

  // MLP
  rmsnorm_kernel<<<MQ, 256, 0, stream>>>(xnew, xn2, nullptr, 0);
  gemm_bt<2,0><<<dim3(32,33), 256, 0, stream>>>(xn2, wfcb, hB, nullptr, MQ, 4096, D_);
  gemm_bt<3,0><<<dim3(8,33),  256, 0, stream>>>(hB, wpb, out, xnew, MQ, D_, 4096);
}

// Round 2
// 512.724 us; speedup vs baseline: 1.1615x; 1.1615x over previous
//
#include <hip/hip_runtime.h>
#include <hip/hip_bf16.h>

// ---- problem constants (from setup_inputs) ----
#define B_   2
#define T_   4160
#define D_   1024
#define H_   16
#define KVH_ 4
#define HD_  64
#define UPD  2048          // update_start
#define NU   2112          // n_update = T - UPD
#define MQ   (B_*NU)       // 4224 rows of updated tokens
#define MT   (B_*T_)       // 8320 rows total

typedef unsigned short u16;
typedef __attribute__((ext_vector_type(8))) short bf16x8;
typedef __attribute__((ext_vector_type(4))) float f32x4;
typedef __attribute__((ext_vector_type(4))) unsigned short u16x4;

__device__ __forceinline__ float bf2f(u16 u){ return __uint_as_float(((unsigned)u)<<16); }
__device__ __forceinline__ u16 f2bf(float f){
  unsigned u = __float_as_uint(f);
  u += 0x7FFF + ((u>>16)&1);           // RNE
  return (u16)(u>>16);
}

// async global->LDS, 16B per lane; lds dst is wave-uniform base (+lane*16 by HW)
__device__ __forceinline__ void gll16(const void* g, void* l){
  __builtin_amdgcn_global_load_lds((const __attribute__((address_space(1))) char*)g,
                                   (__attribute__((address_space(3))) char*)l, 16, 0, 0);
}

// ---------------- elementwise: f32 -> bf16 cast ----------------
__global__ void cast_bf16(const float* __restrict__ in, u16* __restrict__ o, int n){
  int i = blockIdx.x*blockDim.x + threadIdx.x;
  if (i*4 < n){
    float4 v = ((const float4*)in)[i];
    u16x4 u; u.x=f2bf(v.x); u.y=f2bf(v.y); u.z=f2bf(v.z); u.w=f2bf(v.w);
    ((u16x4*)o)[i] = u;
  }
}

// ---------------- RMSNorm (one 256-thread block per row of 1024) ----------------
__global__ void rmsnorm_kernel(const float* __restrict__ in, u16* __restrict__ obf,
                               float* __restrict__ copy_out, int withcopy){
  int row = blockIdx.x;
  int t = threadIdx.x;
  const float* xr = in + (size_t)row*D_;
  float4 v = ((const float4*)xr)[t];
  float ss = v.x*v.x + v.y*v.y + v.z*v.z + v.w*v.w;
  #pragma unroll
  for (int o=32;o;o>>=1) ss += __shfl_xor(ss, o);
  __shared__ float red[4];
  if ((t&63)==0) red[t>>6] = ss;
  __syncthreads();
  float tot = red[0]+red[1]+red[2]+red[3];
  float sc = rsqrtf(tot*(1.0f/D_) + 1e-6f);
  u16x4 o4; o4.x=f2bf(v.x*sc); o4.y=f2bf(v.y*sc); o4.z=f2bf(v.z*sc); o4.w=f2bf(v.w*sc);
  ((u16x4*)(obf + (size_t)row*D_))[t] = o4;
  if (withcopy && (row % T_) < UPD)
    ((float4*)(copy_out + (size_t)row*D_))[t] = v;
}

// ---------------- L2-normalize contiguous 64-element vectors ----------------
__global__ void l2norm_kernel(u16* __restrict__ buf, int nvec){
  int vid = blockIdx.x*4 + (threadIdx.x>>6);
  int ln = threadIdx.x & 63;
  if (vid >= nvec) return;
  u16* p = buf + (size_t)vid*64 + ln;
  float x = bf2f(*p);
  float ss = x*x;
  #pragma unroll
  for (int o=32;o;o>>=1) ss += __shfl_xor(ss, o);
  float n = sqrtf(ss);
  n = (n < 1e-12f) ? 1e-12f : n;
  *p = f2bf(x / n);
}

// ---------------- bf16 GEMM: C[M,N] = A[M,K] * B[N,K]^T ----------------
// 128x128 tile, BK=32, 4 waves (2x2), 16x16x32 MFMA, global_load_lds staging.
// EPI: 0=store bf16   1=softcap-tanh + x residual -> fp32 x_new
//      2=relu^2 -> bf16   3=x_new residual -> fp32 out (row-remapped)
//      5=merged KV: cols<256 -> kB bf16 ; cols>=256 -> vT transposed store
// AMAP: 0 identity; 1: A row r -> (r/NU)*T_ + UPD + r%NU  (x_upd slice of x_norm)
template<int EPI, int AMAP>
__global__ __launch_bounds__(256) void gemm_bt(
    const u16* __restrict__ A, const u16* __restrict__ Bw, void* __restrict__ C,
    void* __restrict__ aux, int M, int N, int K)
{
  __shared__ alignas(16) u16 sA[2][4096];   // [128][32]
  __shared__ alignas(16) u16 sB[2][4096];
  int m0 = blockIdx.y*128, n0 = blockIdx.x*128;
  int tid = threadIdx.x;
  int wv = tid>>6, ln = tid&63;
  int wr = wv>>1, wc = wv&1;
  int lr = ln&15, lg = ln>>4;

  auto stage = [&](int bu, int kt){
    #pragma unroll
    for (int c=0;c<2;c++){
      int ci = c*256 + tid;
      int row = ci>>2, colb = (ci&3)*16;
      int arow = m0 + row;
      if (AMAP==1) arow = (arow/NU)*T_ + UPD + (arow%NU);
      const u16* src = A + (size_t)arow*K + kt*32 + (colb>>1);
      gll16(src, (char*)sA[bu] + (c*256 + wv*64)*16);
    }
    #pragma unroll
    for (int c=0;c<2;c++){
      int ci = c*256 + tid;
      int row = ci>>2, colb = (ci&3)*16;
      const u16* src = Bw + (size_t)(n0+row)*K + kt*32 + (colb>>1);
      gll16(src, (char*)sB[bu] + (c*256 + wv*64)*16);
    }
  };

  f32x4 acc[4][4] = {};
  int nk = K>>5;
  stage(0,0);
  __syncthreads();
  for (int kt=0; kt<nk; ++kt){
    int bu = kt&1;
    if (kt+1<nk) stage(bu^1, kt+1);
    bf16x8 af[4], bfr[4];
    #pragma unroll
    for (int i=0;i<4;i++){
      af[i]  = *(const bf16x8*)&sA[bu][(wr*64 + i*16 + lr)*32 + lg*8];
      bfr[i] = *(const bf16x8*)&sB[bu][(wc*64 + i*16 + lr)*32 + lg*8];
    }
    #pragma unroll
    for (int i=0;i<4;i++)
      #pragma unroll
      for (int j=0;j<4;j++)
        acc[i][j] = __builtin_amdgcn_mfma_f32_16x16x32_bf16(af[i], bfr[j], acc[i][j], 0,0,0);
    __syncthreads();
  }
  #pragma unroll
  for (int i=0;i<4;i++)
    #pragma unroll
    for (int j=0;j<4;j++){
      int grow0 = m0 + wr*64 + i*16 + lg*4;
      int gcol  = n0 + wc*64 + j*16 + lr;
      if (EPI==5){
        if (gcol < 256){
          #pragma unroll
          for (int r=0;r<4;r++)
            ((u16*)C)[(size_t)(grow0+r)*256 + gcol] = f2bf(acc[i][j][r]);
        } else {
          int bb = grow0 / T_;              // grow0 mult of 4, never crosses batch
          int t  = grow0 - bb*T_;
          int kvh = (gcol>>6)&3, d = gcol&63;
          u16x4 pk;
          #pragma unroll
          for (int r=0;r<4;r++) pk[r] = f2bf(acc[i][j][r]);
          *(u16x4*)((u16*)aux + ((size_t)((bb*KVH_+kvh)*64 + d))*T_ + t) = pk;
        }
      } else {
        #pragma unroll
        for (int r=0;r<4;r++){
          int grow = grow0 + r;
          float cv = acc[i][j][r];
          if (EPI==0){
            ((u16*)C)[(size_t)grow*N + gcol] = f2bf(cv);
          } else if (EPI==1){
            int b = grow/NU, t = grow - b*NU;
            float e = __expf(cv*(2.0f/15.0f));
            float val = 15.f*(e-1.f)/(e+1.f) + ((const float*)aux)[((size_t)(b*T_ + UPD + t))*D_ + gcol];
            ((float*)C)[(size_t)grow*N + gcol] = val;
          } else if (EPI==2){
            float rr = cv>0.f ? cv : 0.f;
            ((u16*)C)[(size_t)grow*N + gcol] = f2bf(rr*rr);
          } else {
            int b = grow/NU, t = grow - b*NU;
            float val = ((const float*)aux)[(size_t)grow*N + gcol] + cv;
            ((float*)C)[((size_t)(b*T_ + UPD + t))*D_ + gcol] = val;
          }
        }
      }
    }
}

// ---------------- attention ----------------
// grid (66 qtiles of 32 rows, kh=4, b=2) = 528 blocks, 4 waves.
// Wave w = q-head kh*4+w, 32 q-rows; K/V tiles shared by all 4 heads (staged once).
// V pre-transposed in vT[b][kvh][d][t] by the KV GEMM -> staged via gll16 like K.
// Scores in [-1,1] (L2-normed q,k): exp(s/8) needs no max-tracking; divide at end.
// 2-phase pipeline: stage(next) -> compute(cur) -> one barrier/iter.
// sP XOR-swizzle (q&12)<<3 -> 32-bank conflict-free P writes.
__global__ __launch_bounds__(256) void attn_kernel(
    const u16* __restrict__ qb, const u16* __restrict__ kb,
    const u16* __restrict__ vT, u16* __restrict__ ab)
{
  __shared__ alignas(16) u16 sK[2][64*64];
  __shared__ alignas(16) u16 sV[2][64*64];
  __shared__ alignas(16) u16 sP[4][32*64];
  int qi_blk = 65 - blockIdx.x;              // longest-first
  int kh = blockIdx.y, b = blockIdx.z;
  int tid = threadIdx.x, wv = tid>>6, ln = tid&63;
  int lr = ln&15, lg = ln>>4;
  int h = kh*4 + wv;
  int qrow0 = qi_blk*32;
  int qbg = UPD + qrow0;

  bf16x8 qf[2][2];
  #pragma unroll
  for (int qi=0;qi<2;qi++){
    const u16* qp = qb + (size_t)(b*NU + qrow0 + qi*16 + lr)*D_ + h*HD_;
    qf[qi][0] = *(const bf16x8*)(qp + lg*8);
    qf[qi][1] = *(const bf16x8*)(qp + 32 + lg*8);
  }
  bf16x8 ones;
  #pragma unroll
  for (int i=0;i<8;i++) ones[i] = (short)0x3F80;

  f32x4 accO[2][4] = {};
  f32x4 accD[2] = {};

  auto stage = [&](int bu, int kt){
    #pragma unroll
    for (int cc=0; cc<2; ++cc){
      int ci = cc*256 + tid;
      int row = ci>>3, slotb = (ci&7)*16;
      int scolb = slotb ^ ((row&7)<<4);
      gll16(kb + (size_t)(b*T_ + kt*64 + row)*256 + kh*HD_ + (scolb>>1),
            (char*)sK[bu] + (cc*256 + wv*64)*16);
    }
    #pragma unroll
    for (int cc=0; cc<2; ++cc){
      int ci = cc*256 + tid;
      int row = ci>>3, slotb = (ci&7)*16;     // row = d
      int scolb = slotb ^ ((row&7)<<4);
      gll16(vT + (size_t)((b*KVH_+kh)*64 + row)*T_ + kt*64 + (scolb>>1),
            (char*)sV[bu] + (cc*256 + wv*64)*16);
    }
  };

  int nkt = 33 + (qi_blk>>1);
  stage(0,0);
  __syncthreads();
  for (int kt=0; kt<nkt; ++kt){
    int bu = kt&1;
    if (kt+1 < nkt) stage(bu^1, kt+1);
    // --- S = Q K^T ---
    f32x4 s[2][4];
    #pragma unroll
    for (int qi=0;qi<2;qi++)
      #pragma unroll
      for (int k2=0;k2<4;k2++) s[qi][k2] = (f32x4){0.f,0.f,0.f,0.f};
    #pragma unroll
    for (int k2=0;k2<4;k2++){
      int row = k2*16 + lr;
      int sw = (row&7)<<4;
      bf16x8 k0 = *(const bf16x8*)((const char*)sK[bu] + row*128 + ((lg*16)^sw));
      bf16x8 k1 = *(const bf16x8*)((const char*)sK[bu] + row*128 + ((64+lg*16)^sw));
      #pragma unroll
      for (int qi=0;qi<2;qi++){
        s[qi][k2] = __builtin_amdgcn_mfma_f32_16x16x32_bf16(qf[qi][0], k0, s[qi][k2], 0,0,0);
        s[qi][k2] = __builtin_amdgcn_mfma_f32_16x16x32_bf16(qf[qi][1], k1, s[qi][k2], 0,0,0);
      }
    }
    // --- mask + exp -> sP (swizzled, conflict-free; same-wave so no barrier) ---
    int ktb = kt*64;
    #pragma unroll
    for (int qi=0;qi<2;qi++)
      #pragma unroll
      for (int k2=0;k2<4;k2++)
        #pragma unroll
        for (int r=0;r<4;r++){
          int kpos = ktb + k2*16 + lr;
          int q_l = qi*16 + lg*4 + r;
          float p = (kpos <= qbg + q_l) ? __expf(s[qi][k2][r]*0.125f) : 0.0f;
          int byte = q_l*128 + ((k2*32 + lr*2) ^ ((q_l&12)<<3));
          *(u16*)((char*)sP[wv] + byte) = f2bf(p);
        }
    bf16x8 pf[2][2];
    #pragma unroll
    for (int qi=0;qi<2;qi++)
      #pragma unroll
      for (int hf=0;hf<2;hf++){
        int byte = (qi*16+lr)*128 + ((hf*64 + lg*16) ^ ((lr&12)<<3));
        pf[qi][hf] = *(const bf16x8*)((const char*)sP[wv] + byte);
      }
    // --- O += P V^T, den += P 1 ---
    #pragma unroll
    for (int dt=0; dt<4; ++dt){
      int row = dt*16 + lr;
      int sw = (row&7)<<4;
      bf16x8 v0 = *(const bf16x8*)((const char*)sV[bu] + row*128 + ((lg*16)^sw));
      bf16x8 v1 = *(const bf16x8*)((const char*)sV[bu] + row*128 + ((64+lg*16)^sw));
      #pragma unroll
      for (int qi=0;qi<2;qi++){
        accO[qi][dt] = __builtin_amdgcn_mfma_f32_16x16x32_bf16(pf[qi][0], v0, accO[qi][dt], 0,0,0);
        accO[qi][dt] = __builtin_amdgcn_mfma_f32_16x16x32_bf16(pf[qi][1], v1, accO[qi][dt], 0,0,0);
      }
    }
    #pragma unroll
    for (int qi=0;qi<2;qi++){
      accD[qi] = __builtin_amdgcn_mfma_f32_16x16x32_bf16(pf[qi][0], ones, accD[qi], 0,0,0);
      accD[qi] = __builtin_amdgcn_mfma_f32_16x16x32_bf16(pf[qi][1], ones, accD[qi], 0,0,0);
    }
    __syncthreads();
  }
  #pragma unroll
  for (int qi=0;qi<2;qi++)
    #pragma unroll
    for (int dt=0; dt<4; ++dt)
      #pragma unroll
      for (int r=0;r<4;r++){
        float val = accO[qi][dt][r] / accD[qi][r];
        size_t row = (size_t)(b*NU + qrow0 + qi*16 + lg*4 + r);
        ab[row*D_ + h*HD_ + dt*16 + lr] = f2bf(val);
      }
}

// ---------------- launch ----------------
extern "C" void kernel_launch(void* const* d_in, const int* in_sizes, int n_in,
                              void* d_out, int out_size, void* d_ws, size_t ws_size,
                              hipStream_t stream)
{
  const float* x     = (const float*)d_in[0];
  const float* Wq    = (const float*)d_in[1];
  const float* Wk    = (const float*)d_in[2];
  const float* Wv    = (const float*)d_in[3];
  const float* Wo    = (const float*)d_in[4];
  const float* Wfc   = (const float*)d_in[5];
  const float* Wproj = (const float*)d_in[6];
  float* out = (float*)d_out;

  char* ws = (char*)d_ws;
  size_t off = 0;
  auto alloc = [&](size_t bytes)->char*{ char* p = ws + off; off += (bytes + 255) & ~(size_t)255; return p; };
  u16* wqb  = (u16*)alloc((size_t)D_*D_*2);
  u16* wkvb = (u16*)alloc((size_t)512*D_*2);    // rows 0..255 = Wk, 256..511 = Wv
  u16* wob  = (u16*)alloc((size_t)D_*D_*2);
  u16* wfcb = (u16*)alloc((size_t)4096*D_*2);
  u16* wpb  = (u16*)alloc((size_t)D_*4096*2);
  u16* xn   = (u16*)alloc((size_t)MT*D_*2);
  u16* qB   = (u16*)alloc((size_t)MQ*D_*2);
  u16* kB   = (u16*)alloc((size_t)MT*256*2);
  u16* vTb  = (u16*)alloc((size_t)B_*KVH_*64*T_*2);   // [b][kvh][d][t]
  u16* aB   = (u16*)alloc((size_t)MQ*D_*2);
  float* xnew = (float*)alloc((size_t)MQ*D_*4);
  u16* xn2  = (u16*)alloc((size_t)MQ*D_*2);
  u16* hB   = (u16*)alloc((size_t)MQ*4096*2);
  (void)ws_size; (void)in_sizes; (void)n_in; (void)out_size;

  // weights -> bf16
  cast_bf16<<<1024, 256, 0, stream>>>(Wq, wqb, D_*D_);
  cast_bf16<<<256,  256, 0, stream>>>(Wk, wkvb, 256*D_);
  cast_bf16<<<256,  256, 0, stream>>>(Wv, wkvb + (size_t)256*D_, 256*D_);
  cast_bf16<<<1024, 256, 0, stream>>>(Wo, wob, D_*D_);
  cast_bf16<<<4096, 256, 0, stream>>>(Wfc, wfcb, 4096*D_);
  cast_bf16<<<4096, 256, 0, stream>>>(Wproj, wpb, D_*4096);

  // x_norm (bf16) + passthrough copy of prefix rows to out
  rmsnorm_kernel<<<MT, 256, 0, stream>>>(x, xn, out, 1);

  // projections: Q, and merged KV (K -> kB rows, V -> vT transposed)
  gemm_bt<0,1><<<dim3(8,33),  256, 0, stream>>>(xn, wqb, qB, nullptr, MQ, D_,  D_);
  gemm_bt<5,0><<<dim3(4,65),  256, 0, stream>>>(xn, wkvb, kB, vTb, MT, 512, D_);

  // L2 normalize q and k (not v)
  l2norm_kernel<<<(MQ*H_)/4, 256, 0, stream>>>(qB, MQ*H_);
  l2norm_kernel<<<(MT*KVH_)/4, 256, 0, stream>>>(kB, MT*KVH_);

  // attention
  attn_kernel<<<dim3(66,4,2), 256, 0, stream>>>(qB, kB, vTb, aB);

  // out-proj + softcap + residual -> x_new (fp32)
  gemm_bt<1,0><<<dim3(8,33),  256, 0, stream>>>(aB, wob, xnew, (void*)x, MQ, D_, D_);

  // MLP
  rmsnorm_kernel<<<MQ, 256, 0, stream>>>(xnew, xn2, nullptr, 0);
  gemm_bt<2,0><<<dim3(32,33), 256, 0, stream>>>(xn2, wfcb, hB, nullptr, MQ, 4096, D_);
  gemm_bt<3,0><<<dim3(8,33),  256, 0, stream>>>(hB, wpb, out, xnew, MQ, D_, 4096);
}

// Round 3
// 445.247 us; speedup vs baseline: 1.3375x; 1.1515x over previous
//
#include <hip/hip_runtime.h>
#include <hip/hip_bf16.h>

// ---- problem constants (from setup_inputs) ----
#define B_   2
#define T_   4160
#define D_   1024
#define H_   16
#define KVH_ 4
#define HD_  64
#define UPD  2048          // update_start
#define NU   2112          // n_update = T - UPD
#define MQ   (B_*NU)       // 4224 rows of updated tokens
#define MT   (B_*T_)       // 8320 rows total

typedef unsigned short u16;
typedef unsigned int u32;
typedef __attribute__((ext_vector_type(8))) short bf16x8;
typedef __attribute__((ext_vector_type(4))) float f32x4;
typedef __attribute__((ext_vector_type(4))) unsigned short u16x4;

__device__ __forceinline__ float bf2f(u16 u){ return __uint_as_float(((unsigned)u)<<16); }
__device__ __forceinline__ u16 f2bf(float f){
  unsigned u = __float_as_uint(f);
  u += 0x7FFF + ((u>>16)&1);           // RNE
  return (u16)(u>>16);
}

// async global->LDS, 16B per lane; lds dst is wave-uniform base (+lane*16 by HW)
__device__ __forceinline__ void gll16(const void* g, void* l){
  __builtin_amdgcn_global_load_lds((const __attribute__((address_space(1))) char*)g,
                                   (__attribute__((address_space(3))) char*)l, 16, 0, 0);
}

// ---------------- elementwise: f32 -> bf16 cast ----------------
__global__ void cast_bf16(const float* __restrict__ in, u16* __restrict__ o, int n){
  int i = blockIdx.x*blockDim.x + threadIdx.x;
  if (i*4 < n){
    float4 v = ((const float4*)in)[i];
    u16x4 u; u.x=f2bf(v.x); u.y=f2bf(v.y); u.z=f2bf(v.z); u.w=f2bf(v.w);
    ((u16x4*)o)[i] = u;
  }
}

// ---------------- RMSNorm (one 256-thread block per row of 1024) ----------------
__global__ void rmsnorm_kernel(const float* __restrict__ in, u16* __restrict__ obf,
                               float* __restrict__ copy_out, int withcopy){
  int row = blockIdx.x;
  int t = threadIdx.x;
  const float* xr = in + (size_t)row*D_;
  float4 v = ((const float4*)xr)[t];
  float ss = v.x*v.x + v.y*v.y + v.z*v.z + v.w*v.w;
  #pragma unroll
  for (int o=32;o;o>>=1) ss += __shfl_xor(ss, o);
  __shared__ float red[4];
  if ((t&63)==0) red[t>>6] = ss;
  __syncthreads();
  float tot = red[0]+red[1]+red[2]+red[3];
  float sc = rsqrtf(tot*(1.0f/D_) + 1e-6f);
  u16x4 o4; o4.x=f2bf(v.x*sc); o4.y=f2bf(v.y*sc); o4.z=f2bf(v.z*sc); o4.w=f2bf(v.w*sc);
  ((u16x4*)(obf + (size_t)row*D_))[t] = o4;
  if (withcopy && (row % T_) < UPD)
    ((float4*)(copy_out + (size_t)row*D_))[t] = v;
}

// ---------------- L2-normalize contiguous 64-element vectors ----------------
__global__ void l2norm_kernel(u16* __restrict__ buf, int nvec){
  int vid = blockIdx.x*4 + (threadIdx.x>>6);
  int ln = threadIdx.x & 63;
  if (vid >= nvec) return;
  u16* p = buf + (size_t)vid*64 + ln;
  float x = bf2f(*p);
  float ss = x*x;
  #pragma unroll
  for (int o=32;o;o>>=1) ss += __shfl_xor(ss, o);
  float n = sqrtf(ss);
  n = (n < 1e-12f) ? 1e-12f : n;
  *p = f2bf(x / n);
}

// ---------------- bf16 GEMM: C[M,N] = A[M,K] * B[N,K]^T ----------------
// BM=128, BN in {64,128}. BN=128: 4 waves 2x2, wave=64x64, acc[4][4].
//                          BN=64 : 4 waves 4x1, wave=32x64, acc[2][4].
// BK=32, 16x16x32 MFMA, global_load_lds staging, 2-phase prefetch,
// XCD-aware block swizzle (grid size must be %8==0).
// EPI: 0=store bf16   1=softcap-tanh + x residual -> fp32 x_new
//      2=relu^2 -> bf16   3=x_new residual -> fp32 out (row-remapped)
//      5=merged KV: cols<256 -> kB bf16 ; cols>=256 -> vT transposed store
// AMAP: 0 identity; 1: A row r -> (r/NU)*T_ + UPD + r%NU  (x_upd slice of x_norm)
template<int EPI, int AMAP, int BN>
__global__ __launch_bounds__(256) void gemm_bt(
    const u16* __restrict__ A, const u16* __restrict__ Bw, void* __restrict__ C,
    void* __restrict__ aux, int M, int N, int K)
{
  constexpr int MI = (BN==128) ? 4 : 2;    // 16-row repeats per wave
  __shared__ alignas(16) u16 sA[2][4096];  // [128][32]
  __shared__ alignas(16) u16 sB[2][BN*32];
  // XCD swizzle: each XCD gets a contiguous chunk of row-major tile space
  unsigned nwg = gridDim.x*gridDim.y;
  unsigned flat = blockIdx.y*gridDim.x + blockIdx.x;
  unsigned nf = (flat&7)*(nwg>>3) + (flat>>3);
  int m0 = (int)(nf / gridDim.x) * 128;
  int n0 = (int)(nf % gridDim.x) * BN;
  int tid = threadIdx.x;
  int wv = tid>>6, ln = tid&63;
  int wr = (BN==128) ? (wv>>1) : wv;
  int wc = (BN==128) ? (wv&1)  : 0;
  int lr = ln&15, lg = ln>>4;

  auto stage = [&](int bu, int kt){
    #pragma unroll
    for (int c=0;c<2;c++){
      int ci = c*256 + tid;
      int row = ci>>2, colb = (ci&3)*16;
      int arow = m0 + row;
      if (AMAP==1) arow = (arow/NU)*T_ + UPD + (arow%NU);
      const u16* src = A + (size_t)arow*K + kt*32 + (colb>>1);
      gll16(src, (char*)sA[bu] + (c*256 + wv*64)*16);
    }
    #pragma unroll
    for (int c=0;c<BN/64;c++){
      int ci = c*256 + tid;
      int row = ci>>2, colb = (ci&3)*16;
      const u16* src = Bw + (size_t)(n0+row)*K + kt*32 + (colb>>1);
      gll16(src, (char*)sB[bu] + (c*256 + wv*64)*16);
    }
  };

  f32x4 acc[MI][4] = {};
  int nk = K>>5;
  stage(0,0);
  __syncthreads();
  for (int kt=0; kt<nk; ++kt){
    int bu = kt&1;
    if (kt+1<nk) stage(bu^1, kt+1);
    bf16x8 af[MI], bfr[4];
    #pragma unroll
    for (int i=0;i<MI;i++)
      af[i]  = *(const bf16x8*)&sA[bu][(wr*(MI*16) + i*16 + lr)*32 + lg*8];
    #pragma unroll
    for (int j=0;j<4;j++)
      bfr[j] = *(const bf16x8*)&sB[bu][(wc*64 + j*16 + lr)*32 + lg*8];
    #pragma unroll
    for (int i=0;i<MI;i++)
      #pragma unroll
      for (int j=0;j<4;j++)
        acc[i][j] = __builtin_amdgcn_mfma_f32_16x16x32_bf16(af[i], bfr[j], acc[i][j], 0,0,0);
    __syncthreads();
  }
  #pragma unroll
  for (int i=0;i<MI;i++)
    #pragma unroll
    for (int j=0;j<4;j++){
      int grow0 = m0 + wr*(MI*16) + i*16 + lg*4;
      int gcol  = n0 + wc*64 + j*16 + lr;
      if (EPI==5){
        if (gcol < 256){
          #pragma unroll
          for (int r=0;r<4;r++)
            ((u16*)C)[(size_t)(grow0+r)*256 + gcol] = f2bf(acc[i][j][r]);
        } else {
          int bb = grow0 / T_;              // grow0 mult of 4, never crosses batch
          int t  = grow0 - bb*T_;
          int kvh = (gcol>>6)&3, d = gcol&63;
          u16x4 pk;
          #pragma unroll
          for (int r=0;r<4;r++) pk[r] = f2bf(acc[i][j][r]);
          *(u16x4*)((u16*)aux + ((size_t)((bb*KVH_+kvh)*64 + d))*T_ + t) = pk;
        }
      } else {
        #pragma unroll
        for (int r=0;r<4;r++){
          int grow = grow0 + r;
          float cv = acc[i][j][r];
          if (EPI==0){
            ((u16*)C)[(size_t)grow*N + gcol] = f2bf(cv);
          } else if (EPI==1){
            int b = grow/NU, t = grow - b*NU;
            float e = __expf(cv*(2.0f/15.0f));
            float val = 15.f*(e-1.f)/(e+1.f) + ((const float*)aux)[((size_t)(b*T_ + UPD + t))*D_ + gcol];
            ((float*)C)[(size_t)grow*N + gcol] = val;
          } else if (EPI==2){
            float rr = cv>0.f ? cv : 0.f;
            ((u16*)C)[(size_t)grow*N + gcol] = f2bf(rr*rr);
          } else {
            int b = grow/NU, t = grow - b*NU;
            float val = ((const float*)aux)[(size_t)grow*N + gcol] + cv;
            ((float*)C)[((size_t)(b*T_ + UPD + t))*D_ + gcol] = val;
          }
        }
      }
    }
}

// ---------------- attention softmax+pack helper ----------------
// Swapped S^T layout: lane (lg,lr) holds S[q=qi*16+lr][k=k2*16+lg*4+r].
// Pack 4 P values (k..k+3) -> one 8B LDS write at byte q*128 + ((k*2)^((q&7)<<4)).
template<bool DIAG>
__device__ __forceinline__ void sm_pack(const f32x4 (&s)[2][4], char* spw,
                                        int lr, int lg, int ktb, int qbg){
  #pragma unroll
  for (int qi=0;qi<2;qi++)
    #pragma unroll
    for (int k2=0;k2<4;k2++){
      float p[4];
      #pragma unroll
      for (int r=0;r<4;r++){
        float pv = __builtin_amdgcn_exp2f(s[qi][k2][r]*0.18033688f); // exp(s/8)
        if (DIAG){
          int kpos = ktb + k2*16 + lg*4 + r;
          int qpos = qbg + qi*16 + lr;
          if (kpos > qpos) pv = 0.f;
        }
        p[r] = pv;
      }
      __hip_bfloat162 w0 = __float22bfloat162_rn(float2{p[0],p[1]});
      __hip_bfloat162 w1 = __float22bfloat162_rn(float2{p[2],p[3]});
      uint2 wd; wd.x = *(u32*)&w0; wd.y = *(u32*)&w1;
      *(uint2*)(spw + (qi*16+lr)*128 + ((k2*32 + lg*8) ^ ((lr&7)<<4))) = wd;
    }
}

// ---------------- attention ----------------
// grid (66 qtiles of 32 rows, kh=4, b=2) = 528 blocks, 4 waves.
// Wave w = q-head kh*4+w, 32 q-rows; K/V tiles shared by all 4 heads.
// V pre-transposed in vT[b][kvh][d][t] by the KV GEMM -> staged via gll16.
// Scores in [-1,1] (L2-normed): exp(s/8), no max-tracking; divide at end.
// Swapped QK^T (mfma(K,Q)) -> causal mask only on the diagonal (last) tile;
// P repack via cvt_pk + 8 ds_write_b64 (was 32 ds_write_b16 + XOR math).
// XCD swizzle: each XCD owns one (kh,b) -> KV panel L2-resident.
__global__ __launch_bounds__(256) void attn_kernel(
    const u16* __restrict__ qb, const u16* __restrict__ kb,
    const u16* __restrict__ vT, u16* __restrict__ ab)
{
  __shared__ alignas(16) u16 sK[2][64*64];
  __shared__ alignas(16) u16 sV[2][64*64];
  __shared__ alignas(16) u16 sP[4][32*64];
  unsigned flat = (blockIdx.z*4u + blockIdx.y)*66u + blockIdx.x;
  unsigned nf = (flat&7)*66u + (flat>>3);
  int qi_blk = 65 - (int)(nf % 66u);          // longest-first within XCD
  unsigned khb = nf / 66u;
  int kh = (int)(khb & 3), b = (int)(khb >> 2);
  int tid = threadIdx.x, wv = tid>>6, ln = tid&63;
  int lr = ln&15, lg = ln>>4;
  int h = kh*4 + wv;
  int qrow0 = qi_blk*32;
  int qbg = UPD + qrow0;
  char* spw = (char*)&sP[wv][0];

  bf16x8 qf[2][2];
  #pragma unroll
  for (int qi=0;qi<2;qi++){
    const u16* qp = qb + (size_t)(b*NU + qrow0 + qi*16 + lr)*D_ + h*HD_;
    qf[qi][0] = *(const bf16x8*)(qp + lg*8);
    qf[qi][1] = *(const bf16x8*)(qp + 32 + lg*8);
  }
  bf16x8 ones;
  #pragma unroll
  for (int i=0;i<8;i++) ones[i] = (short)0x3F80;

  f32x4 accO[2][4] = {};
  f32x4 accD[2] = {};

  auto stage = [&](int bu, int kt){
    #pragma unroll
    for (int cc=0; cc<2; ++cc){
      int ci = cc*256 + tid;
      int row = ci>>3, slotb = (ci&7)*16;
      int scolb = slotb ^ ((row&7)<<4);
      gll16(kb + (size_t)(b*T_ + kt*64 + row)*256 + kh*HD_ + (scolb>>1),
            (char*)sK[bu] + (cc*256 + wv*64)*16);
    }
    #pragma unroll
    for (int cc=0; cc<2; ++cc){
      int ci = cc*256 + tid;
      int row = ci>>3, slotb = (ci&7)*16;     // row = d
      int scolb = slotb ^ ((row&7)<<4);
      gll16(vT + (size_t)((b*KVH_+kh)*64 + row)*T_ + kt*64 + (scolb>>1),
            (char*)sV[bu] + (cc*256 + wv*64)*16);
    }
  };

  int nkt = 33 + (qi_blk>>1);
  stage(0,0);
  __syncthreads();
  for (int kt=0; kt<nkt; ++kt){
    int bu = kt&1;
    if (kt+1 < nkt) stage(bu^1, kt+1);
    // --- S^T = K Q^T ---
    f32x4 s[2][4];
    #pragma unroll
    for (int qi=0;qi<2;qi++)
      #pragma unroll
      for (int k2=0;k2<4;k2++) s[qi][k2] = (f32x4){0.f,0.f,0.f,0.f};
    #pragma unroll
    for (int k2=0;k2<4;k2++){
      int row = k2*16 + lr;
      int sw = (row&7)<<4;
      bf16x8 k0 = *(const bf16x8*)((const char*)sK[bu] + row*128 + ((lg*16)^sw));
      bf16x8 k1 = *(const bf16x8*)((const char*)sK[bu] + row*128 + ((64+lg*16)^sw));
      #pragma unroll
      for (int qi=0;qi<2;qi++){
        s[qi][k2] = __builtin_amdgcn_mfma_f32_16x16x32_bf16(k0, qf[qi][0], s[qi][k2], 0,0,0);
        s[qi][k2] = __builtin_amdgcn_mfma_f32_16x16x32_bf16(k1, qf[qi][1], s[qi][k2], 0,0,0);
      }
    }
    // --- exp -> packed bf16 P in LDS (mask only on diagonal tile) ---
    if (kt+1 < nkt) sm_pack<false>(s, spw, lr, lg, kt*64, qbg);
    else            sm_pack<true >(s, spw, lr, lg, kt*64, qbg);
    bf16x8 pf[2][2];
    #pragma unroll
    for (int qi=0;qi<2;qi++)
      #pragma unroll
      for (int hf=0;hf<2;hf++)
        pf[qi][hf] = *(const bf16x8*)(spw + (qi*16+lr)*128 + ((hf*64 + lg*16) ^ ((lr&7)<<4)));
    // --- O += P V^T, den += P 1 ---
    #pragma unroll
    for (int dt=0; dt<4; ++dt){
      int row = dt*16 + lr;
      int sw = (row&7)<<4;
      bf16x8 v0 = *(const bf16x8*)((const char*)sV[bu] + row*128 + ((lg*16)^sw));
      bf16x8 v1 = *(const bf16x8*)((const char*)sV[bu] + row*128 + ((64+lg*16)^sw));
      #pragma unroll
      for (int qi=0;qi<2;qi++){
        accO[qi][dt] = __builtin_amdgcn_mfma_f32_16x16x32_bf16(pf[qi][0], v0, accO[qi][dt], 0,0,0);
        accO[qi][dt] = __builtin_amdgcn_mfma_f32_16x16x32_bf16(pf[qi][1], v1, accO[qi][dt], 0,0,0);
      }
    }
    #pragma unroll
    for (int qi=0;qi<2;qi++){
      accD[qi] = __builtin_amdgcn_mfma_f32_16x16x32_bf16(pf[qi][0], ones, accD[qi], 0,0,0);
      accD[qi] = __builtin_amdgcn_mfma_f32_16x16x32_bf16(pf[qi][1], ones, accD[qi], 0,0,0);
    }
    __syncthreads();
  }
  #pragma unroll
  for (int qi=0;qi<2;qi++)
    #pragma unroll
    for (int dt=0; dt<4; ++dt)
      #pragma unroll
      for (int r=0;r<4;r++){
        float val = accO[qi][dt][r] / accD[qi][r];
        size_t row = (size_t)(b*NU + qrow0 + qi*16 + lg*4 + r);
        ab[row*D_ + h*HD_ + dt*16 + lr] = f2bf(val);
      }
}

// ---------------- launch ----------------
extern "C" void kernel_launch(void* const* d_in, const int* in_sizes, int n_in,
                              void* d_out, int out_size, void* d_ws, size_t ws_size,
                              hipStream_t stream)
{
  const float* x     = (const float*)d_in[0];
  const float* Wq    = (const float*)d_in[1];
  const float* Wk    = (const float*)d_in[2];
  const float* Wv    = (const float*)d_in[3];
  const float* Wo    = (const float*)d_in[4];
  const float* Wfc   = (const float*)d_in[5];
  const float* Wproj = (const float*)d_in[6];
  float* out = (float*)d_out;

  char* ws = (char*)d_ws;
  size_t off = 0;
  auto alloc = [&](size_t bytes)->char*{ char* p = ws + off; off += (bytes + 255) & ~(size_t)255; return p; };
  u16* wqb  = (u16*)alloc((size_t)D_*D_*2);
  u16* wkvb = (u16*)alloc((size_t)512*D_*2);    // rows 0..255 = Wk, 256..511 = Wv
  u16* wob  = (u16*)alloc((size_t)D_*D_*2);
  u16* wfcb = (u16*)alloc((size_t)4096*D_*2);
  u16* wpb  = (u16*)alloc((size_t)D_*4096*2);
  u16* xn   = (u16*)alloc((size_t)MT*D_*2);
  u16* qB   = (u16*)alloc((size_t)MQ*D_*2);
  u16* kB   = (u16*)alloc((size_t)MT*256*2);
  u16* vTb  = (u16*)alloc((size_t)B_*KVH_*64*T_*2);   // [b][kvh][d][t]
  u16* aB   = (u16*)alloc((size_t)MQ*D_*2);
  float* xnew = (float*)alloc((size_t)MQ*D_*4);
  u16* xn2  = (u16*)alloc((size_t)MQ*D_*2);
  u16* hB   = (u16*)alloc((size_t)MQ*4096*2);
  (void)ws_size; (void)in_sizes; (void)n_in; (void)out_size;

  // weights -> bf16
  cast_bf16<<<1024, 256, 0, stream>>>(Wq, wqb, D_*D_);
  cast_bf16<<<256,  256, 0, stream>>>(Wk, wkvb, 256*D_);
  cast_bf16<<<256,  256, 0, stream>>>(Wv, wkvb + (size_t)256*D_, 256*D_);
  cast_bf16<<<1024, 256, 0, stream>>>(Wo, wob, D_*D_);
  cast_bf16<<<4096, 256, 0, stream>>>(Wfc, wfcb, 4096*D_);
  cast_bf16<<<4096, 256, 0, stream>>>(Wproj, wpb, D_*4096);

  // x_norm (bf16) + passthrough copy of prefix rows to out
  rmsnorm_kernel<<<MT, 256, 0, stream>>>(x, xn, out, 1);

  // projections: Q (BN=64), merged KV (BN=64; K -> kB rows, V -> vT transposed)
  gemm_bt<0,1,64><<<dim3(16,33), 256, 0, stream>>>(xn, wqb, qB, nullptr, MQ, D_,  D_);
  gemm_bt<5,0,64><<<dim3(8,65),  256, 0, stream>>>(xn, wkvb, kB, vTb, MT, 512, D_);

  // L2 normalize q and k (not v)
  l2norm_kernel<<<(MQ*H_)/4, 256, 0, stream>>>(qB, MQ*H_);
  l2norm_kernel<<<(MT*KVH_)/4, 256, 0, stream>>>(kB, MT*KVH_);

  // attention
  attn_kernel<<<dim3(66,4,2), 256, 0, stream>>>(qB, kB, vTb, aB);

  // out-proj + softcap + residual -> x_new (fp32)
  gemm_bt<1,0,64><<<dim3(16,33), 256, 0, stream>>>(aB, wob, xnew, (void*)x, MQ, D_, D_);

  // MLP
  rmsnorm_kernel<<<MQ, 256, 0, stream>>>(xnew, xn2, nullptr, 0);
  gemm_bt<2,0,128><<<dim3(32,33), 256, 0, stream>>>(xn2, wfcb, hB, nullptr, MQ, 4096, D_);
  gemm_bt<3,0,64><<<dim3(16,33), 256, 0, stream>>>(hB, wpb, out, xnew, MQ, D_, 4096);
}